// Round 3
// baseline (273.988 us; speedup 1.0000x reference)
//
#include <hip/hip_runtime.h>

// out[b,s,i*64+j] = max(x[b,s,i], kernel[i,j])
// B=8, S=2048, I=64, O=64. Output = 16,777,216 float4 = 256 MiB. Write-bound.
//
// Key layout fact: with stride = grid*block = 2^20 float4s (a multiple of 1024),
// each thread's in-row position rem = v & 1023 is LOOP-INVARIANT:
//   - the kernel float4 it needs (km4[rem]) is ONE register value -> no LDS,
//     no staging, no __syncthreads, no LDS occupancy cap.
//   - i = rem>>4 is constant; only row (= v>>10) advances, by +1024/iter.
// Exact cover: 4096 blocks x 256 threads x 16 float4/thread = 2^24 = total4.
// Loads are prefetched 4-at-a-time so waits are vmcnt-counted and the
// dwordx4 store stream stays deep. Non-temporal stores keep the 256 MB
// write stream from evicting x (4 MiB) / km (16 KiB) out of L2.
//
// NOTE 1: __builtin_nontemporal_store requires a native clang vector type,
//         not HIP's float4 class -> use ext_vector_type(4) float.
// NOTE 2: out_size from the harness is in ELEMENTS (fp32 count = 2^26),
//         not bytes -> total4 = out_size / 4. (Round-2 bug: >>4 gave a
//         1024-block grid that covered only 1/4 of the output.)

typedef __attribute__((ext_vector_type(4))) float f32x4;

__global__ __launch_bounds__(256) void fuzzy_max_kernel(
    const float* __restrict__ x,
    const float* __restrict__ km,
    f32x4* __restrict__ out) {
  const unsigned t = threadIdx.x;
  const unsigned v0 = (blockIdx.x << 8) | t;   // first float4 index, < 2^20
  const unsigned rem = v0 & 1023u;             // loop-invariant row position
  const unsigned i = rem >> 4;                 // input-feature index (constant)

  // One 16 B load per thread for its kernel fragment; lanes read consecutive
  // float4s -> coalesced, L2-broadcast across all 4096 blocks.
  const f32x4 k = reinterpret_cast<const f32x4*>(km)[rem];

  const float* xp = x + i;                     // x[(row<<6) | i] == xp[row<<6]
  const unsigned row0 = v0 >> 10;              // rows step by +1024 per iter

#pragma unroll
  for (int mm = 0; mm < 4; ++mm) {
    // Batch 4 independent x loads (same 64 B line shared by 16 lanes each,
    // L1/L2-hot) so their latency overlaps and store waits are counted.
    float xs[4];
#pragma unroll
    for (int u = 0; u < 4; ++u) {
      const unsigned row = row0 + (unsigned)(mm * 4 + u) * 1024u;
      xs[u] = xp[(size_t)row << 6];
    }
#pragma unroll
    for (int u = 0; u < 4; ++u) {
      f32x4 o;
      o.x = fmaxf(xs[u], k.x);
      o.y = fmaxf(xs[u], k.y);
      o.z = fmaxf(xs[u], k.z);
      o.w = fmaxf(xs[u], k.w);
      const unsigned v = v0 + (unsigned)(mm * 4 + u) * 1048576u;
      __builtin_nontemporal_store(o, &out[v]);  // coalesced 1 KB/wave store
    }
  }
}

extern "C" void kernel_launch(void* const* d_in, const int* in_sizes, int n_in,
                              void* d_out, int out_size, void* d_ws, size_t ws_size,
                              hipStream_t stream) {
  const float* x = reinterpret_cast<const float*>(d_in[0]);   // (8,2048,64) fp32
  const float* km = reinterpret_cast<const float*>(d_in[1]);  // (64,64) fp32
  f32x4* out = reinterpret_cast<f32x4*>(d_out);

  // out_size is fp32 ELEMENT count (2^26) -> total4 = 2^24 float4s.
  // Each thread handles exactly 16 float4s: grid = total4 / (256*16) = 4096.
  const unsigned total4 = (unsigned)(out_size / 4);
  const int block = 256;
  const int grid = (int)(total4 >> 12);  // 4096 for the fixed shape
  fuzzy_max_kernel<<<grid, block, 0, stream>>>(x, km, out);
}

// Round 4
// 272.855 us; speedup vs baseline: 1.0041x; 1.0041x over previous
//
#include <hip/hip_runtime.h>

// out[b,s,i*64+j] = max(x[b,s,i], kernel[i,j])
// B=8, S=2048, I=64, O=64. Output = 16,777,216 float4 = 256 MiB. Write-bound.
//
// Round-3 post-mortem: two different kernels both ran ~105 us (~2.6 TB/s)
// while the harness's own 1 GiB fill hits 6.4 TB/s. Shared traits were
// (a) load/store interleaving (vmcnt waits for x-loads drain the store
// FIFO every iteration) and (b) 4 KiB-per-block write chunks strided by
// 16 MiB. This version removes both:
//   - Each block owns a CONTIGUOUS 64 KiB output span = 4 full (b,s) rows
//     (4096 float4). 4096 blocks cover the 2^24 float4 output exactly.
//   - ALL loads are hoisted: 4 kernel float4s (km4[c*256+t], c=0..3) and
//     16 x scalars (4 rows x 4 i-positions) are independent and issued
//     before any store. After one vmcnt wait the epilogue is 64 fmax +
//     16 back-to-back global_store_dwordx4 -> a pure, deep store stream.
//
// Index algebra (v = out float4 index = blk*4096 + (r*4+c)*256 + t):
//   row = v>>10 = 4*blk + r;  rem = v&1023 = c*256 + t
//   i   = rem>>4 = c*16 + (t>>4);  kernel float4 = km4[i*16 + (t&15)]
//       = km4[c*256 + t]  -> per-thread fragments kf[c], c=0..3.
//   x value = x[row*64 + i] = x[blk*256 + r*64 + c*16 + (t>>4)]
//
// NOTE: out_size from the harness is in ELEMENTS (2^26 fp32), not bytes.

typedef __attribute__((ext_vector_type(4))) float f32x4;

__global__ __launch_bounds__(256) void fuzzy_max_kernel(
    const float* __restrict__ x,
    const float* __restrict__ km,
    f32x4* __restrict__ out) {
  const unsigned t = threadIdx.x;
  const unsigned blk = blockIdx.x;

  const f32x4* km4 = reinterpret_cast<const f32x4*>(km);
  // 4 kernel fragments this thread ever needs (coalesced across lanes).
  f32x4 kf[4];
#pragma unroll
  for (int c = 0; c < 4; ++c) kf[c] = km4[c * 256u + t];

  // 16 x scalars: 4 rows (r) x 4 in-row i-positions (c). 16-lane broadcast
  // per load, 1 KiB of x per block total, L1/L2-hot. All independent.
  const float* xb = x + (size_t)blk * 256u;  // = x + (4*blk)*64
  const unsigned i0 = t >> 4;
  float xv[4][4];
#pragma unroll
  for (int r = 0; r < 4; ++r)
#pragma unroll
    for (int c = 0; c < 4; ++c)
      xv[r][c] = xb[r * 64u + c * 16u + i0];

  // Pure store stream: 16 contiguous-coalesced dwordx4 stores, no loads
  // in between -> no vmcnt wait ever drains the store FIFO mid-stream.
  f32x4* ob = out + (size_t)blk * 4096u;
#pragma unroll
  for (int r = 0; r < 4; ++r) {
#pragma unroll
    for (int c = 0; c < 4; ++c) {
      const float xs = xv[r][c];
      f32x4 o;
      o.x = fmaxf(xs, kf[c].x);
      o.y = fmaxf(xs, kf[c].y);
      o.z = fmaxf(xs, kf[c].z);
      o.w = fmaxf(xs, kf[c].w);
      __builtin_nontemporal_store(o, &ob[(r * 4u + c) * 256u + t]);
    }
  }
}

extern "C" void kernel_launch(void* const* d_in, const int* in_sizes, int n_in,
                              void* d_out, int out_size, void* d_ws, size_t ws_size,
                              hipStream_t stream) {
  const float* x = reinterpret_cast<const float*>(d_in[0]);   // (8,2048,64) fp32
  const float* km = reinterpret_cast<const float*>(d_in[1]);  // (64,64) fp32
  f32x4* out = reinterpret_cast<f32x4*>(d_out);

  // out_size is fp32 ELEMENT count (2^26) -> total4 = 2^24 float4s.
  // Each block writes 4096 contiguous float4s (64 KiB): grid = 4096.
  const unsigned total4 = (unsigned)(out_size / 4);
  const int block = 256;
  const int grid = (int)(total4 >> 12);
  fuzzy_max_kernel<<<grid, block, 0, stream>>>(x, km, out);
}